// Round 1
// baseline (206.245 us; speedup 1.0000x reference)
//
#include <hip/hip_runtime.h>

#define NN 4096
#define FIN 256
#define CC 256
#define NHEADS 8
#define HDIM 32
#define NEG_SLOPE 0.2f

#define BI 32
#define JB 32
#define WH 36                 // padded head stride in w_lds (floats)
#define WJ (NHEADS * WH)      // 288 floats per j row

// ---------------- K1: g = h @ W ----------------
__global__ __launch_bounds__(256) void k_gemm(const float* __restrict__ h,
                                              const float* __restrict__ W,
                                              float* __restrict__ g) {
  __shared__ float hs[16][FIN];
  const int r0 = blockIdx.x * 16;
  const int t = threadIdx.x;
  for (int idx = t; idx < 16 * FIN / 4; idx += 256) {
    const int r = idx >> 6, c4 = idx & 63;
    *(float4*)&hs[r][c4 * 4] =
        *(const float4*)&h[(size_t)(r0 + r) * FIN + c4 * 4];
  }
  __syncthreads();
  const int c = t;
  float acc[16];
#pragma unroll
  for (int r = 0; r < 16; ++r) acc[r] = 0.f;
  for (int k = 0; k < FIN; k += 4) {
    const float w0 = W[(size_t)(k + 0) * CC + c];
    const float w1 = W[(size_t)(k + 1) * CC + c];
    const float w2 = W[(size_t)(k + 2) * CC + c];
    const float w3 = W[(size_t)(k + 3) * CC + c];
#pragma unroll
    for (int r = 0; r < 16; ++r) {
      const float4 hv = *(const float4*)&hs[r][k];
      acc[r] += hv.x * w0 + hv.y * w1 + hv.z * w2 + hv.w * w3;
    }
  }
#pragma unroll
  for (int r = 0; r < 16; ++r) g[(size_t)(r0 + r) * CC + c] = acc[r];
}

// ---------------- K2: s_src / s_dst ----------------
__global__ __launch_bounds__(256) void k_scores(const float* __restrict__ g,
                                                const float* __restrict__ a,
                                                float* __restrict__ s_src,
                                                float* __restrict__ s_dst) {
  const int idx = blockIdx.x * 256 + threadIdx.x;  // n*NHEADS + h
  const float* gp = g + (size_t)idx * HDIM;
  float ss = 0.f, sd = 0.f;
#pragma unroll
  for (int f = 0; f < HDIM; f += 4) {
    const float4 gv = *(const float4*)&gp[f];
    ss += gv.x * a[f + 0] + gv.y * a[f + 1] + gv.z * a[f + 2] + gv.w * a[f + 3];
    sd += gv.x * a[HDIM + f + 0] + gv.y * a[HDIM + f + 1] +
          gv.z * a[HDIM + f + 2] + gv.w * a[HDIM + f + 3];
  }
  s_src[idx] = ss;
  s_dst[idx] = sd;
}

// ---------------- K3: fused masked-exp + PV ----------------
// grid = (NN/BI) * splits, block = 256
// phase-A thread identity: (i_a = t>>3, h_a = t&7) owns one (i,h) pair
// phase-B thread identity: (fg = t&3, hb = (t>>2)&7, ig = t>>5) -> 4i x 8f tile
__global__ __launch_bounds__(256, 2) void k_attn(
    const int* __restrict__ adj, const float* __restrict__ g,
    const float* __restrict__ s_src, const float* __restrict__ s_dst,
    float* __restrict__ acc_ws, float* __restrict__ l_ws,
    float* __restrict__ out, const int splits, const int direct) {
  __shared__ float g_lds[JB][CC];        // 32 KB
  __shared__ float w_lds[JB][WJ];        // 36 KB
  __shared__ int adj_lds[BI][JB + 1];    // 4.2 KB (padded row -> no bank clash)
  __shared__ float sdst_lds[JB][NHEADS]; // 1 KB
  __shared__ float ssrc_lds[BI * NHEADS];
  __shared__ float l_lds[BI * NHEADS];

  const int t = threadIdx.x;
  const int bx = blockIdx.x;
  const int sp = bx & (splits - 1);  // splits is a power of 2
  const int ib = bx / splits;
  const int i0 = ib * BI;
  const int jrange = NN / splits;
  const int j0b = sp * jrange;

  const int i_a = t >> 3, h_a = t & 7;
  ssrc_lds[t] = s_src[(size_t)i0 * NHEADS + t];

  const int fg = t & 3, hb = (t >> 2) & 7, ig = t >> 5;
  const int f0 = fg * 8, ir = ig * 4;

  float acc[4][8];
#pragma unroll
  for (int x = 0; x < 4; ++x)
#pragma unroll
    for (int y = 0; y < 8; ++y) acc[x][y] = 0.f;
  float l_acc = 0.f;

  __syncthreads();
  const float ss = ssrc_lds[i_a * NHEADS + h_a];

  const int nchunk = jrange / JB;
  for (int jc = 0; jc < nchunk; ++jc) {
    const int j0 = j0b + jc * JB;
    __syncthreads();  // previous phase-B done before restaging
    {  // stage adj chunk: 32x32 ints, one int4 per thread
      const int r = t >> 3, c4 = t & 7;
      const int4 v = *(const int4*)&adj[(size_t)(i0 + r) * NN + j0 + c4 * 4];
      adj_lds[r][c4 * 4 + 0] = v.x;
      adj_lds[r][c4 * 4 + 1] = v.y;
      adj_lds[r][c4 * 4 + 2] = v.z;
      adj_lds[r][c4 * 4 + 3] = v.w;
    }
    // stage s_dst chunk (exactly 256 contiguous floats)
    ((float*)sdst_lds)[t] = s_dst[(size_t)j0 * NHEADS + t];
    // stage g chunk: 32 rows x 256 floats
#pragma unroll
    for (int k = 0; k < 8; ++k) {
      const int lin4 = t + k * 256;
      const int j = lin4 >> 6, c4 = lin4 & 63;
      *(float4*)&g_lds[j][c4 * 4] =
          *(const float4*)&g[(size_t)(j0 + j) * CC + c4 * 4];
    }
    __syncthreads();
    // phase A: w[j][h][i] = adj * exp(leaky(s_src+s_dst)); accumulate l
#pragma unroll 4
    for (int j = 0; j < JB; ++j) {
      float x = ss + sdst_lds[j][h_a];
      x = x > 0.f ? x : NEG_SLOPE * x;
      const float w = __expf(x) * (float)adj_lds[i_a][j];
      w_lds[j][h_a * WH + i_a] = w;
      l_acc += w;
    }
    __syncthreads();
    // phase B: acc[i][f] += w[j][h][i] * g[j][h][f]
#pragma unroll 4
    for (int j = 0; j < JB; ++j) {
      const float4 wv = *(const float4*)&w_lds[j][hb * WH + ir];
      const float4 ga = *(const float4*)&g_lds[j][hb * HDIM + f0];
      const float4 gb = *(const float4*)&g_lds[j][hb * HDIM + f0 + 4];
      const float w4[4] = {wv.x, wv.y, wv.z, wv.w};
      const float gg[8] = {ga.x, ga.y, ga.z, ga.w, gb.x, gb.y, gb.z, gb.w};
#pragma unroll
      for (int di = 0; di < 4; ++di)
#pragma unroll
        for (int df = 0; df < 8; ++df) acc[di][df] += w4[di] * gg[df];
    }
  }

  if (direct) {
    l_lds[i_a * NHEADS + h_a] = l_acc;
    __syncthreads();
#pragma unroll
    for (int di = 0; di < 4; ++di) {
      const float inv = 1.f / l_lds[(ir + di) * NHEADS + hb];
      float* p = out + (size_t)(i0 + ir + di) * CC + hb * HDIM + f0;
      *(float4*)&p[0] = make_float4(acc[di][0] * inv, acc[di][1] * inv,
                                    acc[di][2] * inv, acc[di][3] * inv);
      *(float4*)&p[4] = make_float4(acc[di][4] * inv, acc[di][5] * inv,
                                    acc[di][6] * inv, acc[di][7] * inv);
    }
  } else {
    l_ws[((size_t)sp * NN + i0 + i_a) * NHEADS + h_a] = l_acc;
#pragma unroll
    for (int di = 0; di < 4; ++di) {
      float* p = acc_ws + ((size_t)sp * NN + i0 + ir + di) * CC + hb * HDIM + f0;
      *(float4*)&p[0] =
          make_float4(acc[di][0], acc[di][1], acc[di][2], acc[di][3]);
      *(float4*)&p[4] =
          make_float4(acc[di][4], acc[di][5], acc[di][6], acc[di][7]);
    }
  }
}

// ---------------- K4: combine partials ----------------
__global__ __launch_bounds__(256) void k_combine(
    const float* __restrict__ acc_ws, const float* __restrict__ l_ws,
    float* __restrict__ out, const int splits) {
  const int idx = blockIdx.x * 256 + threadIdx.x;  // float4 index
  const int row = idx >> 6;
  const int c4 = idx & 63;
  const int hh = c4 >> 3;
  float ax = 0.f, ay = 0.f, az = 0.f, aw = 0.f, l = 0.f;
  for (int s = 0; s < splits; ++s) {
    const float4 v =
        *(const float4*)&acc_ws[((size_t)s * NN + row) * CC + c4 * 4];
    ax += v.x; ay += v.y; az += v.z; aw += v.w;
    l += l_ws[((size_t)s * NN + row) * NHEADS + hh];
  }
  const float inv = 1.f / l;
  *(float4*)&out[(size_t)row * CC + c4 * 4] =
      make_float4(ax * inv, ay * inv, az * inv, aw * inv);
}

extern "C" void kernel_launch(void* const* d_in, const int* in_sizes, int n_in,
                              void* d_out, int out_size, void* d_ws,
                              size_t ws_size, hipStream_t stream) {
  (void)in_sizes; (void)n_in; (void)out_size;
  const float* h = (const float*)d_in[0];
  const int* adj = (const int*)d_in[1];
  const float* W = (const float*)d_in[2];
  const float* a = (const float*)d_in[3];
  float* out = (float*)d_out;
  float* ws = (float*)d_ws;

  float* g = ws;                                    // NN*CC
  float* s_src = g + (size_t)NN * CC;               // NN*NHEADS
  float* s_dst = s_src + (size_t)NN * NHEADS;       // NN*NHEADS
  float* acc_ws = s_dst + (size_t)NN * NHEADS;

  const size_t base_f = (size_t)NN * CC + 2 * (size_t)NN * NHEADS;
  int splits = 1;
  {
    const size_t need4 =
        (base_f + 4 * ((size_t)NN * CC + (size_t)NN * NHEADS)) * 4;
    const size_t need2 =
        (base_f + 2 * ((size_t)NN * CC + (size_t)NN * NHEADS)) * 4;
    if (ws_size >= need4) splits = 4;
    else if (ws_size >= need2) splits = 2;
  }

  k_gemm<<<NN / 16, 256, 0, stream>>>(h, W, g);
  k_scores<<<NN * NHEADS / 256, 256, 0, stream>>>(g, a, s_src, s_dst);

  if (splits == 1) {
    k_attn<<<NN / BI, 256, 0, stream>>>(adj, g, s_src, s_dst, nullptr, nullptr,
                                        out, 1, 1);
  } else {
    float* l_ws = acc_ws + (size_t)splits * NN * CC;
    k_attn<<<(NN / BI) * splits, 256, 0, stream>>>(adj, g, s_src, s_dst,
                                                   acc_ws, l_ws, out, splits, 0);
    k_combine<<<NN * CC / 4 / 256, 256, 0, stream>>>(acc_ws, l_ws, out, splits);
  }
}

// Round 2
// 97.803 us; speedup vs baseline: 2.1088x; 2.1088x over previous
//
#include <hip/hip_runtime.h>
#include <hip/hip_bf16.h>

#define NN 4096
#define FIN 256
#define CC 256
#define NH 8

typedef __attribute__((ext_vector_type(8))) short short8;
typedef __attribute__((ext_vector_type(4))) float f32x4;

__device__ __forceinline__ unsigned short bf16rn(float x) {
  unsigned int u = __builtin_bit_cast(unsigned int, x);
  u += 0x7fffu + ((u >> 16) & 1u);
  return (unsigned short)(u >> 16);
}

// ---------------- K1: g = h@W, fused epilogue ----------------
// writes gT (bf16, [c=h*32+f][n]) and score packs:
//   spack[h][n] = (s_src, e^s, e^{0.2s}, 0), dpack likewise for s_dst
#define GROWS 8
__global__ __launch_bounds__(256) void k_gemm(
    const float* __restrict__ h, const float* __restrict__ W,
    const float* __restrict__ a, unsigned short* __restrict__ gT,
    float4* __restrict__ spack, float4* __restrict__ dpack) {
  __shared__ float hs[GROWS][FIN];
  const int r0 = blockIdx.x * GROWS;
  const int t = threadIdx.x;
#pragma unroll
  for (int idx = t; idx < GROWS * FIN / 4; idx += 256) {
    const int r = idx >> 6, c4 = idx & 63;
    *(float4*)&hs[r][c4 * 4] =
        *(const float4*)&h[(size_t)(r0 + r) * FIN + c4 * 4];
  }
  __syncthreads();
  const int c = t;
  float acc[GROWS];
#pragma unroll
  for (int r = 0; r < GROWS; ++r) acc[r] = 0.f;
  for (int k = 0; k < FIN; k += 4) {
    const float w0 = W[(size_t)(k + 0) * CC + c];
    const float w1 = W[(size_t)(k + 1) * CC + c];
    const float w2 = W[(size_t)(k + 2) * CC + c];
    const float w3 = W[(size_t)(k + 3) * CC + c];
#pragma unroll
    for (int r = 0; r < GROWS; ++r) {
      const float4 hv = *(const float4*)&hs[r][k];
      acc[r] += hv.x * w0 + hv.y * w1 + hv.z * w2 + hv.w * w3;
    }
  }
  const int f = c & 31, hh = c >> 5;
  const float aS = a[f], aD = a[32 + f];
  unsigned short gu[GROWS];
#pragma unroll
  for (int r = 0; r < GROWS; ++r) {
    float ps = acc[r] * aS, pd = acc[r] * aD;
#pragma unroll
    for (int m = 1; m < 32; m <<= 1) {
      ps += __shfl_xor(ps, m, 64);
      pd += __shfl_xor(pd, m, 64);
    }
    if (f == 0) {
      const int n = r0 + r;
      spack[(size_t)hh * NN + n] =
          make_float4(ps, __expf(ps), __expf(0.2f * ps), 0.f);
      dpack[(size_t)hh * NN + n] =
          make_float4(pd, __expf(pd), __expf(0.2f * pd), 0.f);
    }
    gu[r] = bf16rn(acc[r]);
  }
  uint4 gv;
  gv.x = (unsigned)gu[0] | ((unsigned)gu[1] << 16);
  gv.y = (unsigned)gu[2] | ((unsigned)gu[3] << 16);
  gv.z = (unsigned)gu[4] | ((unsigned)gu[5] << 16);
  gv.w = (unsigned)gu[6] | ((unsigned)gu[7] << 16);
  *(uint4*)(gT + (size_t)c * NN + r0) = gv;
}

// ---------------- K2: fused masked-softmax-weight + MFMA PV ----------------
// block = 256 thr (4 waves). wave w handles heads {2w, 2w+1}.
// A-frag (w-matrix) computed in registers: lane l -> i = it*16 + (l&15),
// j = 8*(l>>4)+e (contiguous-8 k layout). B-frag from gT_lds via ds_read_b128.
__global__ __launch_bounds__(256, 2) void k_attn(
    const int* __restrict__ adj, const unsigned short* __restrict__ gT,
    const float4* __restrict__ spack, const float4* __restrict__ dpack,
    float* __restrict__ acc_ws, float* __restrict__ l_ws,
    float* __restrict__ out, const int splits, const int direct) {
  __shared__ unsigned short gt_lds[256][40];  // [c][j] pad 40 -> bank-spread
  __shared__ int adj_lds[32][36];
  __shared__ float sd_lds[3][NH][32];         // (sd, e1d, e2d)
  __shared__ float l_lds[NH][32];

  const int t = threadIdx.x;
  const int lane = t & 63, w = t >> 6;
  const int il = lane & 15, q = lane >> 4;
  const int bx = blockIdx.x;
  const int sp = bx & (splits - 1);
  const int ib = bx / splits;
  const int i0 = ib * 32;
  const int jrange = NN / splits;
  const int j0b = sp * jrange;

  // hoisted i-side scalars
  float ssv[2][2], e1i[2][2], e2i[2][2];
#pragma unroll
  for (int hp = 0; hp < 2; ++hp) {
    const int hh = 2 * w + hp;
#pragma unroll
    for (int it = 0; it < 2; ++it) {
      const float4 v = spack[(size_t)hh * NN + i0 + it * 16 + il];
      ssv[hp][it] = v.x; e1i[hp][it] = v.y; e2i[hp][it] = v.z;
    }
  }

  f32x4 acc[2][2][2];
  float lacc[2][2];
#pragma unroll
  for (int hp = 0; hp < 2; ++hp)
#pragma unroll
    for (int it = 0; it < 2; ++it) {
      lacc[hp][it] = 0.f;
#pragma unroll
      for (int ft = 0; ft < 2; ++ft)
#pragma unroll
        for (int r = 0; r < 4; ++r) acc[hp][it][ft][r] = 0.f;
    }

  // reg-staged prefetch (T14): gT row 64B + adj 16B + dpack 16B per thread
  uint4 pg0, pg1, pg2, pg3;
  int4 pa;
  float4 pd;
  const int ar = t >> 3, aseg = t & 7;
  const int dh = t >> 5, dj = t & 31;
  auto issue = [&](int j0) {
    const uint4* gs = (const uint4*)(gT + (size_t)t * NN + j0);
    pg0 = gs[0]; pg1 = gs[1]; pg2 = gs[2]; pg3 = gs[3];
    pa = *(const int4*)&adj[(size_t)(i0 + ar) * NN + j0 + aseg * 4];
    pd = dpack[(size_t)dh * NN + j0 + dj];
  };
  issue(j0b);

  const int nch = jrange / 32;
  for (int jc = 0; jc < nch; ++jc) {
    __syncthreads();  // previous chunk's readers done
    {
      uint4* gd = (uint4*)&gt_lds[t][0];
      gd[0] = pg0; gd[1] = pg1; gd[2] = pg2; gd[3] = pg3;
    }
    *(int4*)&adj_lds[ar][aseg * 4] = pa;
    sd_lds[0][dh][dj] = pd.x;
    sd_lds[1][dh][dj] = pd.y;
    sd_lds[2][dh][dj] = pd.z;
    __syncthreads();
    if (jc + 1 < nch) issue(j0b + (jc + 1) * 32);  // overlap with compute

#pragma unroll
    for (int hp = 0; hp < 2; ++hp) {
      const int hh = 2 * w + hp;
      float sdj[8], e1j[8], e2j[8];
      *(float4*)&sdj[0] = *(const float4*)&sd_lds[0][hh][q * 8];
      *(float4*)&sdj[4] = *(const float4*)&sd_lds[0][hh][q * 8 + 4];
      *(float4*)&e1j[0] = *(const float4*)&sd_lds[1][hh][q * 8];
      *(float4*)&e1j[4] = *(const float4*)&sd_lds[1][hh][q * 8 + 4];
      *(float4*)&e2j[0] = *(const float4*)&sd_lds[2][hh][q * 8];
      *(float4*)&e2j[4] = *(const float4*)&sd_lds[2][hh][q * 8 + 4];
      short8 bfr0 = *(const short8*)&gt_lds[hh * 32 + il][q * 8];
      short8 bfr1 = *(const short8*)&gt_lds[hh * 32 + 16 + il][q * 8];
#pragma unroll
      for (int it = 0; it < 2; ++it) {
        int adjv[8];
        *(int4*)&adjv[0] = *(const int4*)&adj_lds[it * 16 + il][q * 8];
        *(int4*)&adjv[4] = *(const int4*)&adj_lds[it * 16 + il][q * 8 + 4];
        const float ssl = ssv[hp][it];
        const float E1 = e1i[hp][it], E2 = e2i[hp][it];
        short8 afr;
        float ls = 0.f;
#pragma unroll
        for (int e = 0; e < 8; ++e) {
          const float x = ssl + sdj[e];
          const bool pos = x > 0.f;
          const float ei = pos ? E1 : E2;
          const float ej = pos ? e1j[e] : e2j[e];
          float wv = ei * ej;
          wv = (adjv[e] != 0) ? wv : 0.f;
          ls += wv;
          afr[e] = (short)bf16rn(wv);
        }
        lacc[hp][it] += ls;
        acc[hp][it][0] = __builtin_amdgcn_mfma_f32_16x16x32_bf16(
            afr, bfr0, acc[hp][it][0], 0, 0, 0);
        acc[hp][it][1] = __builtin_amdgcn_mfma_f32_16x16x32_bf16(
            afr, bfr1, acc[hp][it][1], 0, 0, 0);
      }
    }
  }

  // reduce l over the 4 k-quarters (lanes sharing il)
#pragma unroll
  for (int hp = 0; hp < 2; ++hp)
#pragma unroll
    for (int it = 0; it < 2; ++it) {
      float v = lacc[hp][it];
      v += __shfl_xor(v, 16, 64);
      v += __shfl_xor(v, 32, 64);
      lacc[hp][it] = v;
    }

  if (direct) {
    if (q == 0) {
#pragma unroll
      for (int hp = 0; hp < 2; ++hp)
#pragma unroll
        for (int it = 0; it < 2; ++it)
          l_lds[2 * w + hp][it * 16 + il] = lacc[hp][it];
    }
    __syncthreads();
#pragma unroll
    for (int hp = 0; hp < 2; ++hp) {
      const int hh = 2 * w + hp;
#pragma unroll
      for (int it = 0; it < 2; ++it)
#pragma unroll
        for (int ft = 0; ft < 2; ++ft)
#pragma unroll
          for (int r = 0; r < 4; ++r) {
            const int irow = it * 16 + q * 4 + r;
            const float inv = 1.f / l_lds[hh][irow];
            out[(size_t)(i0 + irow) * CC + hh * 32 + ft * 16 + il] =
                acc[hp][it][ft][r] * inv;
          }
    }
  } else {
    if (q == 0) {
#pragma unroll
      for (int hp = 0; hp < 2; ++hp)
#pragma unroll
        for (int it = 0; it < 2; ++it)
          l_ws[((size_t)sp * NH + 2 * w + hp) * NN + i0 + it * 16 + il] =
              lacc[hp][it];
    }
#pragma unroll
    for (int hp = 0; hp < 2; ++hp) {
      const int hh = 2 * w + hp;
#pragma unroll
      for (int it = 0; it < 2; ++it)
#pragma unroll
        for (int ft = 0; ft < 2; ++ft)
#pragma unroll
          for (int r = 0; r < 4; ++r) {
            const int irow = it * 16 + q * 4 + r;
            acc_ws[((size_t)sp * NN + i0 + irow) * CC + hh * 32 + ft * 16 +
                   il] = acc[hp][it][ft][r];
          }
    }
  }
}

// ---------------- K3: combine split partials ----------------
__global__ __launch_bounds__(256) void k_combine(
    const float* __restrict__ acc_ws, const float* __restrict__ l_ws,
    float* __restrict__ out, const int splits) {
  const int idx = blockIdx.x * 256 + threadIdx.x;  // float4 index
  const int row = idx >> 6, c4 = idx & 63;
  const int hh = c4 >> 3;
  float ax = 0.f, ay = 0.f, az = 0.f, aw = 0.f, l = 0.f;
  for (int s = 0; s < splits; ++s) {
    const float4 v =
        *(const float4*)&acc_ws[((size_t)s * NN + row) * CC + c4 * 4];
    ax += v.x; ay += v.y; az += v.z; aw += v.w;
    l += l_ws[((size_t)s * NH + hh) * NN + row];
  }
  const float inv = 1.f / l;
  *(float4*)&out[(size_t)row * CC + c4 * 4] =
      make_float4(ax * inv, ay * inv, az * inv, aw * inv);
}

extern "C" void kernel_launch(void* const* d_in, const int* in_sizes, int n_in,
                              void* d_out, int out_size, void* d_ws,
                              size_t ws_size, hipStream_t stream) {
  (void)in_sizes; (void)n_in; (void)out_size;
  const float* h = (const float*)d_in[0];
  const int* adj = (const int*)d_in[1];
  const float* W = (const float*)d_in[2];
  const float* a = (const float*)d_in[3];
  float* out = (float*)d_out;
  char* ws = (char*)d_ws;

  unsigned short* gT = (unsigned short*)ws;                 // 2 MB
  float4* spack = (float4*)(ws + (size_t)NN * CC * 2);      // 512 KB
  float4* dpack = spack + (size_t)NH * NN;                  // 512 KB
  char* after = (char*)(dpack + (size_t)NH * NN);
  const size_t base = (size_t)(after - ws);
  const size_t per_split = (size_t)NN * CC * 4 + (size_t)NH * NN * 4;

  int splits = 1;
  if (ws_size >= base + 4 * per_split) splits = 4;
  else if (ws_size >= base + 2 * per_split) splits = 2;

  k_gemm<<<NN / GROWS, 256, 0, stream>>>(h, W, a, gT, spack, dpack);

  if (splits == 1) {
    k_attn<<<NN / 32, 256, 0, stream>>>(adj, gT, spack, dpack, nullptr,
                                        nullptr, out, 1, 1);
  } else {
    float* acc_ws = (float*)after;
    float* l_ws = acc_ws + (size_t)splits * NN * CC;
    k_attn<<<(NN / 32) * splits, 256, 0, stream>>>(
        adj, gT, spack, dpack, acc_ws, l_ws, out, splits, 0);
    k_combine<<<NN * CC / 4 / 256, 256, 0, stream>>>(acc_ws, l_ws, out,
                                                     splits);
  }
}